// Round 5
// baseline (316.221 us; speedup 1.0000x reference)
//
#include <hip/hip_runtime.h>
#include <hip/hip_bf16.h>
#include <cstdint>
#include <cstddef>

// ---------------------------------------------------------------------------
// E3nnMLPNorm: only the l=1 (d=3) irrep path is nonzero.
// layer0 (K=2) -> [gemm(+fused colsumsq) -> bn+gate] x5 -> final dot
// Precision: bf16 hi+lo pairs, 3 bf16 MFMA per fragment into f32 acc.
// GEMM: 128x128 tile, 512 threads = 8 waves as 2 K-groups of 4 waves.
// Each group double-buffers its K-half (2-phase, counted vmcnt(8)); the
// two groups occupy each SIMD with 2 waves in different pipeline phases
// (TLP latency hiding — R4 showed 1 wave/SIMD exposes all latency).
// Cross-group accumulator combine via LDS, then fused column-sumsq.
// ---------------------------------------------------------------------------

typedef short    s16x8 __attribute__((ext_vector_type(8)));
typedef float    f32x4 __attribute__((ext_vector_type(4)));

#define PLANE 1048576   // 1024*1024 elements per plane

__device__ __forceinline__ unsigned short f2bf(float f) {
  unsigned u = __builtin_bit_cast(unsigned, f);
  u += 0x7FFFu + ((u >> 16) & 1u);              // round-to-nearest-even
  return (unsigned short)(u >> 16);
}
__device__ __forceinline__ float bf2f(unsigned short h) {
  return __builtin_bit_cast(float, (unsigned)h << 16);
}

__device__ __forceinline__ void load_lds16(const void* g, void* l) {
  __builtin_amdgcn_global_load_lds(
      (const __attribute__((address_space(1))) unsigned int*)g,
      (__attribute__((address_space(3))) unsigned int*)l,
      16, 0, 0);
}

// ---- W[b,0] (f32 [u][v]) -> bf16 hi/lo [v][u] with 1/32 folded in ----------
__global__ void convert_w(const float* __restrict__ W,
                          unsigned short* __restrict__ Wh,
                          unsigned short* __restrict__ Wl) {
  __shared__ float t[64][65];
  const int u0 = blockIdx.x * 64, v0 = blockIdx.y * 64;
  const float* Wb = W + (size_t)blockIdx.z * 4194304;   // [5][4][1024][1024], irrep 0
  unsigned short* Whb = Wh + (size_t)blockIdx.z * PLANE;
  unsigned short* Wlb = Wl + (size_t)blockIdx.z * PLANE;
  const int c = threadIdx.x & 63, r4 = threadIdx.x >> 6;
#pragma unroll
  for (int i = 0; i < 16; ++i) {
    const int r = i * 4 + r4;
    t[r][c] = Wb[(size_t)(u0 + r) * 1024 + v0 + c];
  }
  __syncthreads();
#pragma unroll
  for (int i = 0; i < 16; ++i) {
    const int r = i * 4 + r4;   // local v index
    const float w = t[c][r] * 0.03125f;      // exact pow2 scale
    const unsigned short hi = f2bf(w);
    const size_t idx = (size_t)(v0 + r) * 1024 + u0 + c;
    Whb[idx] = hi;
    Wlb[idx] = f2bf(w - bf2f(hi));
  }
}

// ---- layer0: pre[i][b][v] = (x[b,0,i]*w1[0,v] + x[b,1,i]*w1[1,v]) / sqrt(2) -
__global__ void layer0(const float* __restrict__ x, const float* __restrict__ w1,
                       float* __restrict__ pre) {
  const int gid = blockIdx.x * 256 + threadIdx.x;   // b*1024 + v
  const int v = gid & 1023, b = gid >> 10;
  const float a0 = w1[v], a1 = w1[1024 + v];
  const float* xb = x + b * 6;                      // x flat [B][2][3]
  const float inv = 0.70710678118654752f;
#pragma unroll
  for (int i = 0; i < 3; ++i)
    pre[(size_t)i * PLANE + gid] = (xb[i] * a0 + xb[3 + i] * a1) * inv;
}

// ---- column sum of squares (layer0 only) -> var[v] (atomic) -----------------
__global__ void colsumsq(const float* __restrict__ pre, float* __restrict__ var) {
  const int col = blockIdx.y * 256 + threadIdx.x;
  const int r0 = blockIdx.x * 128;                  // 24 row-chunks of 128
  float s = 0.f;
#pragma unroll 4
  for (int r = 0; r < 128; ++r) {
    const float v = pre[(size_t)(r0 + r) * 1024 + col];
    s += v * v;
  }
  atomicAdd(&var[col], s);
}

// ---- batchnorm scale + norm-gated sigmoid, write bf16 hi/lo (x4 vector) -----
__global__ void act_kernel(const float* __restrict__ pre, const float* __restrict__ var,
                           const float* __restrict__ bnw,
                           unsigned short* __restrict__ ah,
                           unsigned short* __restrict__ al) {
  const int idx = (blockIdx.x * 256 + threadIdx.x) * 4;   // 262144 threads x4
  const int v = idx & 1023;
  const float4 p0 = *(const float4*)&pre[idx];
  const float4 p1 = *(const float4*)&pre[idx + PLANE];
  const float4 p2 = *(const float4*)&pre[idx + 2 * PLANE];
  const float a0[4] = {p0.x, p0.y, p0.z, p0.w};
  const float a1[4] = {p1.x, p1.y, p1.z, p1.w};
  const float a2[4] = {p2.x, p2.y, p2.z, p2.w};
  unsigned short H0[4], L0[4], H1[4], L1[4], H2[4], L2[4];
#pragma unroll
  for (int j = 0; j < 4; ++j) {
    const float s = bnw[v + j] / sqrtf(var[v + j] * (1.0f / 3072.0f) + 1e-5f);
    const float f0 = a0[j] * s, f1 = a1[j] * s, f2 = a2[j] * s;
    const float n = sqrtf(f0 * f0 + f1 * f1 + f2 * f2 + 1e-8f);
    const float g = 1.0f / ((1.0f + expf(-n)) * n);   // sigmoid(n)/n
    const float o0 = f0 * g, o1 = f1 * g, o2 = f2 * g;
    H0[j] = f2bf(o0); L0[j] = f2bf(o0 - bf2f(H0[j]));
    H1[j] = f2bf(o1); L1[j] = f2bf(o1 - bf2f(H1[j]));
    H2[j] = f2bf(o2); L2[j] = f2bf(o2 - bf2f(H2[j]));
  }
  *(ushort4*)&ah[idx]             = make_ushort4(H0[0], H0[1], H0[2], H0[3]);
  *(ushort4*)&al[idx]             = make_ushort4(L0[0], L0[1], L0[2], L0[3]);
  *(ushort4*)&ah[idx + PLANE]     = make_ushort4(H1[0], H1[1], H1[2], H1[3]);
  *(ushort4*)&al[idx + PLANE]     = make_ushort4(L1[0], L1[1], L1[2], L1[3]);
  *(ushort4*)&ah[idx + 2 * PLANE] = make_ushort4(H2[0], H2[1], H2[2], H2[3]);
  *(ushort4*)&al[idx + 2 * PLANE] = make_ushort4(L2[0], L2[1], L2[2], L2[3]);
}

// ---- bf16-pair MFMA GEMM + fused column-sumsq, 8-wave 2-K-group -------------
// C[3072][1024] = (Ah+Al) * (Bh+Bl)^T ; var[col] += sum_rows C^2
__global__ __launch_bounds__(512) void gemm_fused(
    const unsigned short* __restrict__ Ah, const unsigned short* __restrict__ Al,
    const unsigned short* __restrict__ Bh, const unsigned short* __restrict__ Bl,
    float* __restrict__ C, float* __restrict__ var) {
  // [grp][buf][mat: aH,aL,bH,bL][kc][row][8 halves] = 128 KB
  __shared__ unsigned short lds[2][2][4][4][128][8];
  const int tid = threadIdx.x;
  // XCD swizzle: 192 blocks = 8 XCDs x 24; give each XCD one bn column-panel
  const int bid = blockIdx.y * 24 + blockIdx.x;
  const int nbid = (bid & 7) * 24 + (bid >> 3);
  const int bm0 = (nbid % 24) * 128, bn0 = (nbid / 24) * 128;

  const int lane = tid & 63;
  const int grp  = tid >> 8;              // K-group: 0 or 1
  const int t256 = tid & 255;             // thread id within group
  const int wig  = t256 >> 6;             // wave in group: 0..3
  const int wm = (wig >> 1) * 64, wn = (wig & 1) * 64;
  const int rsel = lane & 15, kcsel = lane >> 4;

  f32x4 acc[4][4] = {};

  // global staging: thread covers (row = t256&127, 16B chunk = t256>>7),
  // K byte-offset grp*1024 + t*64
  const size_t rowoff = ((size_t)(t256 & 127) << 11) + ((t256 >> 7) << 4)
                      + ((size_t)grp << 10);
  const char* g0 = (const char*)Ah + ((size_t)bm0 << 11) + rowoff;
  const char* g1 = (const char*)Al + ((size_t)bm0 << 11) + rowoff;
  const char* g2 = (const char*)Bh + ((size_t)bn0 << 11) + rowoff;
  const char* g3 = (const char*)Bl + ((size_t)bn0 << 11) + rowoff;

  auto stage = [&](int buf, int t) {
    const int kb = t << 6;                               // byte offset in K-half
    char* base = (char*)lds + (grp << 16) + (buf << 15) + (wig << 10);
    load_lds16(g0 + kb, base);          load_lds16(g0 + kb + 32, base + 4096);
    load_lds16(g1 + kb, base + 8192);   load_lds16(g1 + kb + 32, base + 12288);
    load_lds16(g2 + kb, base + 16384);  load_lds16(g2 + kb + 32, base + 20480);
    load_lds16(g3 + kb, base + 24576);  load_lds16(g3 + kb + 32, base + 28672);
  };

  auto compute = [&](int buf) {
    s16x8 fah[4], fal[4], fbh[4], fbl[4];
#pragma unroll
    for (int m = 0; m < 4; ++m) {
      fah[m] = *(const s16x8*)&lds[grp][buf][0][kcsel][wm + m * 16 + rsel][0];
      fal[m] = *(const s16x8*)&lds[grp][buf][1][kcsel][wm + m * 16 + rsel][0];
    }
#pragma unroll
    for (int n = 0; n < 4; ++n) {
      fbh[n] = *(const s16x8*)&lds[grp][buf][2][kcsel][wn + n * 16 + rsel][0];
      fbl[n] = *(const s16x8*)&lds[grp][buf][3][kcsel][wn + n * 16 + rsel][0];
    }
#pragma unroll
    for (int m = 0; m < 4; ++m)
#pragma unroll
      for (int n = 0; n < 4; ++n) {
        acc[m][n] = __builtin_amdgcn_mfma_f32_16x16x32_bf16(fal[m], fbh[n], acc[m][n], 0, 0, 0);
        acc[m][n] = __builtin_amdgcn_mfma_f32_16x16x32_bf16(fah[m], fbl[n], acc[m][n], 0, 0, 0);
        acc[m][n] = __builtin_amdgcn_mfma_f32_16x16x32_bf16(fah[m], fbh[n], acc[m][n], 0, 0, 0);
      }
  };

  stage(0, 0);                                     // prologue
  for (int t = 0; t < 15; ++t) {
    stage((t + 1) & 1, t + 1);                     // prefetch next K-step
    __builtin_amdgcn_sched_barrier(0);
    asm volatile("s_waitcnt vmcnt(8)" ::: "memory");  // wait stage(t) only
    __builtin_amdgcn_sched_barrier(0);
    __builtin_amdgcn_s_barrier();
    compute(t & 1);
    __builtin_amdgcn_sched_barrier(0);
    __builtin_amdgcn_s_barrier();                  // protect buf before overwrite
  }
  __builtin_amdgcn_sched_barrier(0);
  asm volatile("s_waitcnt vmcnt(0)" ::: "memory");
  __builtin_amdgcn_sched_barrier(0);
  __builtin_amdgcn_s_barrier();
  compute(1);                                      // t=15

  // ---- cross-group combine via LDS (group 1 -> group 0) ----
  __syncthreads();
  float* red = (float*)lds;                        // reuse staging LDS (64 KB)
  if (grp == 1) {
    float* wr = red + (wig << 12);                 // 4096 f32 per wave
#pragma unroll
    for (int m = 0; m < 4; ++m)
#pragma unroll
      for (int n = 0; n < 4; ++n)
#pragma unroll
        for (int j = 0; j < 4; ++j)
          wr[((((m << 2) | n) << 2) | j) << 6 | lane] = acc[m][n][j];
  }
  __syncthreads();
  if (grp == 0) {
    const float* rd = red + (wig << 12);
    // D row = (lane>>4)*4 + j, col = lane&15  [m89-verified layout]
    const int r0 = bm0 + wm + (kcsel << 2);
    const int c0 = bn0 + wn + rsel;
    float csq[4] = {0.f, 0.f, 0.f, 0.f};
#pragma unroll
    for (int m = 0; m < 4; ++m)
#pragma unroll
      for (int n = 0; n < 4; ++n)
#pragma unroll
        for (int j = 0; j < 4; ++j) {
          const float v = acc[m][n][j] + rd[((((m << 2) | n) << 2) | j) << 6 | lane];
          C[(size_t)(r0 + m * 16 + j) * 1024 + c0 + n * 16] = v;
          csq[n] += v * v;
        }
    // reduce over kcsel lanes: lanes rsel, +16, +32, +48
#pragma unroll
    for (int n = 0; n < 4; ++n) {
      csq[n] += __shfl_xor(csq[n], 16);
      csq[n] += __shfl_xor(csq[n], 32);
    }
    if (kcsel == 0) {
#pragma unroll
      for (int n = 0; n < 4; ++n)
        atomicAdd(&var[c0 + n * 16], csq[n]);
    }
  }
}

// ---- final: out[b,i] = (1/32) * sum_v act[i][b][v] * wout[v] ----------------
__global__ void final_kernel(const unsigned short* __restrict__ ah,
                             const unsigned short* __restrict__ al,
                             const float* __restrict__ wout, float* __restrict__ out) {
  const int b = blockIdx.x, tid = threadIdx.x;
  __shared__ float red[3][4];
  float s[3] = {0.f, 0.f, 0.f};
  for (int v = tid; v < 1024; v += 256) {
    const float w = wout[v];
    const size_t base = (size_t)b * 1024 + v;
    s[0] += (bf2f(ah[base])             + bf2f(al[base]))             * w;
    s[1] += (bf2f(ah[base + PLANE])     + bf2f(al[base + PLANE]))     * w;
    s[2] += (bf2f(ah[base + 2 * PLANE]) + bf2f(al[base + 2 * PLANE])) * w;
  }
#pragma unroll
  for (int i = 0; i < 3; ++i)
    for (int o = 32; o >= 1; o >>= 1) s[i] += __shfl_down(s[i], o);
  if ((tid & 63) == 0)
#pragma unroll
    for (int i = 0; i < 3; ++i) red[i][tid >> 6] = s[i];
  __syncthreads();
  if (tid < 3) {
    const float t = red[tid][0] + red[tid][1] + red[tid][2] + red[tid][3];
    out[b * 3 + tid] = t * 0.03125f;
  }
}

extern "C" void kernel_launch(void* const* d_in, const int* in_sizes, int n_in,
                              void* d_out, int out_size, void* d_ws, size_t ws_size,
                              hipStream_t stream) {
  const float* x    = (const float*)d_in[0];
  const float* w1   = (const float*)d_in[1];
  const float* W    = (const float*)d_in[2];
  const float* bnw  = (const float*)d_in[3];
  const float* wout = (const float*)d_in[4];
  float* out = (float*)d_out;

  char* ws = (char*)d_ws;
  float*          var = (float*)ws;                         // 6*1024 f32 (32 KB resv)
  float*          pre = (float*)(ws + 32768);               // 3072*1024 f32 (12 MB)
  unsigned short* ah  = (unsigned short*)(ws + 12615680);   // 3*1M bf16 (6 MB)
  unsigned short* al  = (unsigned short*)(ws + 18907136);   // 3*1M bf16 (6 MB)
  unsigned short* wh  = (unsigned short*)(ws + 25198592);   // 5*1M bf16 (10 MB)
  unsigned short* wl  = (unsigned short*)(ws + 35684352);   // 5*1M bf16 (10 MB)

  hipMemsetAsync(var, 0, 6 * 1024 * sizeof(float), stream);
  convert_w<<<dim3(16, 16, 5), 256, 0, stream>>>(W, wh, wl);
  layer0<<<4096, 256, 0, stream>>>(x, w1, pre);
  colsumsq<<<dim3(24, 4), 256, 0, stream>>>(pre, var);
  act_kernel<<<1024, 256, 0, stream>>>(pre, var, bnw, ah, al);
  for (int b = 0; b < 5; ++b) {
    gemm_fused<<<dim3(24, 8), 512, 0, stream>>>(
        ah, al, wh + (size_t)b * PLANE, wl + (size_t)b * PLANE,
        pre, var + (b + 1) * 1024);
    act_kernel<<<1024, 256, 0, stream>>>(pre, var + (b + 1) * 1024,
                                         bnw + (size_t)(b + 1) * 4096, ah, al);
  }
  final_kernel<<<1024, 256, 0, stream>>>(ah, al, wout, out);
}